// Round 3
// baseline (695.875 us; speedup 1.0000x reference)
//
#include <hip/hip_runtime.h>

typedef __bf16 bf16;
typedef __bf16 bf16x8 __attribute__((ext_vector_type(8)));
typedef float f32x4 __attribute__((ext_vector_type(4)));

#define B_SZ   8
#define L_SEQ  1024
#define NH     16

// NaN scrub: fmaxf(NaN, -C) -> -C (AMD IEEE minNum/maxNum), distinct C per stage = tag.
__device__ __forceinline__ float scrub(float x, float c) {
  return fminf(fmaxf(x, -c), c);
}

// load 8 contiguous f32, convert to bf16x8
__device__ __forceinline__ bf16x8 cvt8(const float* __restrict__ p) {
  f32x4 a = *(const f32x4*)p;
  f32x4 b = *(const f32x4*)(p + 4);
  bf16x8 r;
  r[0] = (bf16)a[0]; r[1] = (bf16)a[1]; r[2] = (bf16)a[2]; r[3] = (bf16)a[3];
  r[4] = (bf16)b[0]; r[5] = (bf16)b[1]; r[6] = (bf16)b[2]; r[7] = (bf16)b[3];
  return r;
}

// ---------------------------------------------------------------------------
// GEMM: out = A @ W^T + bias.  W: NxK row-major f32.  A: MxK row-major,
//   aMode 0: A is f32    aMode 1: A is bf16
//   oMode 0: f32 out[i*N+j]
//   oMode 1: bf16 out[((b*16+h)*1024+l)*64+d]   (head-split; i=b*1024+l, j=h*64+d)
//   oMode 2: bf16 out[((b*16+h)*64+d)*1024+l]   (head-split + transpose, for V)
// Tile 128x128, BK=64, 4 waves 2x2, each wave 64x64 via 4x4 16x16x32 MFMA.
// ---------------------------------------------------------------------------
__global__ __launch_bounds__(256) void gemm_bt(const void* __restrict__ Ap,
                                               const float* __restrict__ W,
                                               const float* __restrict__ bias,
                                               void* __restrict__ outp,
                                               int M, int N, int K,
                                               int aMode, int oMode) {
  const int tid  = threadIdx.x;
  const int wave = tid >> 6;
  const int lane = tid & 63;
  const int quad = lane >> 4;
  const int l16  = lane & 15;
  const int wr   = wave >> 1;
  const int wc   = wave & 1;
  const int bm   = blockIdx.y * 128;
  const int bn   = blockIdx.x * 128;

  __shared__ __align__(16) bf16 a_s[128][72];
  __shared__ __align__(16) bf16 b_s[128][72];

  f32x4 acc[4][4] = {};

  for (int kt = 0; kt < K; kt += 64) {
    __syncthreads();
    for (int i = 0; i < 4; i++) {
      int c = tid + i * 256;
      int row = c >> 3;
      int cg = (c & 7) * 8;
      if (aMode == 0)
        *(bf16x8*)&a_s[row][cg] = cvt8((const float*)Ap + (size_t)(bm + row) * K + kt + cg);
      else
        *(bf16x8*)&a_s[row][cg] = *(const bf16x8*)((const bf16*)Ap + (size_t)(bm + row) * K + kt + cg);
      *(bf16x8*)&b_s[row][cg] = cvt8(W + (size_t)(bn + row) * K + kt + cg);
    }
    __syncthreads();

    for (int ks = 0; ks < 2; ks++) {
      bf16x8 af[4], bfr[4];
      for (int mt = 0; mt < 4; mt++)
        af[mt] = *(const bf16x8*)&a_s[wr * 64 + mt * 16 + l16][ks * 32 + quad * 8];
      for (int nt = 0; nt < 4; nt++)
        bfr[nt] = *(const bf16x8*)&b_s[wc * 64 + nt * 16 + l16][ks * 32 + quad * 8];
      for (int mt = 0; mt < 4; mt++)
        for (int nt = 0; nt < 4; nt++)
          acc[mt][nt] = __builtin_amdgcn_mfma_f32_16x16x32_bf16(af[mt], bfr[nt], acc[mt][nt], 0, 0, 0);
    }
  }

  for (int mt = 0; mt < 4; mt++) {
    for (int nt = 0; nt < 4; nt++) {
      int col = bn + wc * 64 + nt * 16 + l16;
      float bv = bias[col];
      for (int r = 0; r < 4; r++) {
        int i = bm + wr * 64 + mt * 16 + quad * 4 + r;
        float v = scrub(acc[mt][nt][r] + bv, 1e33f);
        if (oMode == 0) {
          ((float*)outp)[(size_t)i * N + col] = v;
        } else {
          int b = i >> 10, l = i & 1023;
          int h = col >> 6, d = col & 63;
          size_t off = (oMode == 1) ? ((size_t)(b * 16 + h) * 1024 + l) * 64 + d
                                    : ((size_t)(b * 16 + h) * 64 + d) * 1024 + l;
          ((bf16*)outp)[off] = (bf16)v;
        }
      }
    }
  }
}

// ---------------------------------------------------------------------------
// t = T @ WT^T + bT.  T: 8192x64 f32, WT: 64x64 f32.  out: 8192x64 bf16.
// ---------------------------------------------------------------------------
__global__ __launch_bounds__(256) void t_proj(const float* __restrict__ T,
                                              const float* __restrict__ WT,
                                              const float* __restrict__ bT,
                                              bf16* __restrict__ tout) {
  const int tid  = threadIdx.x;
  const int wave = tid >> 6;
  const int lane = tid & 63;
  const int quad = lane >> 4;
  const int l16  = lane & 15;
  const int row0 = blockIdx.x * 64;

  __shared__ __align__(16) bf16 t_s[64][72];
  __shared__ __align__(16) bf16 w_s[64][72];

  for (int i = 0; i < 2; i++) {
    int c = tid + i * 256;
    int r = c >> 3;
    int cg = (c & 7) * 8;
    *(bf16x8*)&t_s[r][cg] = cvt8(T + (size_t)(row0 + r) * 64 + cg);
    *(bf16x8*)&w_s[r][cg] = cvt8(WT + (size_t)r * 64 + cg);
  }
  __syncthreads();

  f32x4 acc[4] = {};
  for (int ks = 0; ks < 2; ks++) {
    bf16x8 a = *(const bf16x8*)&t_s[wave * 16 + l16][ks * 32 + quad * 8];
    for (int nt = 0; nt < 4; nt++) {
      bf16x8 b = *(const bf16x8*)&w_s[nt * 16 + l16][ks * 32 + quad * 8];
      acc[nt] = __builtin_amdgcn_mfma_f32_16x16x32_bf16(a, b, acc[nt], 0, 0, 0);
    }
  }
  for (int nt = 0; nt < 4; nt++) {
    int col = nt * 16 + l16;
    float bv = bT[col];
    for (int r = 0; r < 4; r++) {
      int row = row0 + wave * 16 + quad * 4 + r;
      tout[(size_t)row * 64 + col] = (bf16)scrub(acc[nt][r] + bv, 1e35f);
    }
  }
}

// ---------------------------------------------------------------------------
// Flash attention per (bh, 64-row q-tile). All operands bf16 in ws / d_out.
// ---------------------------------------------------------------------------
__global__ __launch_bounds__(256) void attn(const bf16* __restrict__ qh,
                                            const bf16* __restrict__ kh,
                                            const bf16* __restrict__ vT,
                                            const bf16* __restrict__ tb,
                                            const int* __restrict__ mask,
                                            bf16* __restrict__ xout) {
  const int qt   = blockIdx.x;        // 0..15
  const int bh   = blockIdx.y;        // 0..127
  const int b    = bh >> 4;
  const int h    = bh & 15;
  const int tid  = threadIdx.x;
  const int wave = tid >> 6;
  const int lane = tid & 63;
  const int quad = lane >> 4;
  const int l16  = lane & 15;

  __shared__ __align__(16) bf16 q_s[64][136];
  __shared__ __align__(16) bf16 k_s[64][136];
  __shared__ __align__(16) bf16 v_s[64][72];
  __shared__ __align__(16) bf16 p_s[64][72];

  const bf16* qb  = qh + ((size_t)bh * L_SEQ + qt * 64) * 64;
  const bf16* tqb = tb + ((size_t)b * L_SEQ + qt * 64) * 64;
  const bf16* kb0 = kh + (size_t)bh * L_SEQ * 64;
  const bf16* tb0 = tb + (size_t)b * L_SEQ * 64;
  const bf16* vb  = vT + (size_t)bh * 64 * L_SEQ;
  const int* mb   = mask + (size_t)b * L_SEQ * L_SEQ;

  for (int i = 0; i < 4; i++) {
    int c = tid + i * 256;
    int row = c >> 4;
    int cg = c & 15;
    const bf16* src = (cg < 8) ? (qb + row * 64 + cg * 8) : (tqb + row * 64 + (cg - 8) * 8);
    *(bf16x8*)&q_s[row][cg * 8] = *(const bf16x8*)src;
  }

  f32x4 o[4] = {};
  float m_prev[4], l_prev[4];
  for (int r = 0; r < 4; r++) { m_prev[r] = -1e30f; l_prev[r] = 0.f; }

  const float scale = 0.08838834764831845f;  // 1/sqrt(128)
  const int qrow_base = qt * 64 + wave * 16 + quad * 4;

  for (int kt = 0; kt < 16; kt++) {
    __syncthreads();
    for (int i = 0; i < 4; i++) {
      int c = tid + i * 256;
      int row = c >> 4;
      int cg = c & 15;
      const bf16* src = (cg < 8) ? (kb0 + (size_t)(kt * 64 + row) * 64 + cg * 8)
                                 : (tb0 + (size_t)(kt * 64 + row) * 64 + (cg - 8) * 8);
      *(bf16x8*)&k_s[row][cg * 8] = *(const bf16x8*)src;
    }
    for (int i = 0; i < 2; i++) {
      int c = tid + i * 256;
      int row = c >> 3;
      int cg = (c & 7) * 8;
      *(bf16x8*)&v_s[row][cg] = *(const bf16x8*)&vb[(size_t)row * L_SEQ + kt * 64 + cg];
    }
    __syncthreads();

    f32x4 s_acc[4] = {};
    for (int ks = 0; ks < 4; ks++) {
      bf16x8 a = *(const bf16x8*)&q_s[wave * 16 + l16][ks * 32 + quad * 8];
      for (int nt = 0; nt < 4; nt++) {
        bf16x8 bfr = *(const bf16x8*)&k_s[nt * 16 + l16][ks * 32 + quad * 8];
        s_acc[nt] = __builtin_amdgcn_mfma_f32_16x16x32_bf16(a, bfr, s_acc[nt], 0, 0, 0);
      }
    }

    float sv[4][4];
    for (int nt = 0; nt < 4; nt++) {
      int kcol = kt * 64 + nt * 16 + l16;
      for (int r = 0; r < 4; r++) {
        int mval = mb[(size_t)(qrow_base + r) * L_SEQ + kcol];
        float s = fminf(fmaxf(s_acc[nt][r] * scale, -1e9f), 1e9f);
        sv[nt][r] = (mval != 0) ? -1e9f : s;
      }
    }

    float alpha[4];
    for (int r = 0; r < 4; r++) {
      float mx = fmaxf(fmaxf(sv[0][r], sv[1][r]), fmaxf(sv[2][r], sv[3][r]));
      for (int off = 8; off >= 1; off >>= 1) mx = fmaxf(mx, __shfl_xor(mx, off));
      float m_new = fmaxf(m_prev[r], mx);
      alpha[r] = __expf(m_prev[r] - m_new);
      float rowsum = 0.f;
      for (int nt = 0; nt < 4; nt++) {
        float p = __expf(sv[nt][r] - m_new);
        sv[nt][r] = p;
        rowsum += p;
      }
      for (int off = 8; off >= 1; off >>= 1) rowsum += __shfl_xor(rowsum, off);
      l_prev[r] = l_prev[r] * alpha[r] + rowsum;
      m_prev[r] = m_new;
    }
    for (int nt = 0; nt < 4; nt++)
      for (int r = 0; r < 4; r++) o[nt][r] *= alpha[r];

    for (int nt = 0; nt < 4; nt++)
      for (int r = 0; r < 4; r++)
        p_s[wave * 16 + quad * 4 + r][nt * 16 + l16] = (bf16)sv[nt][r];
    __syncthreads();

    for (int ks = 0; ks < 2; ks++) {
      bf16x8 a = *(const bf16x8*)&p_s[wave * 16 + l16][ks * 32 + quad * 8];
      for (int nt = 0; nt < 4; nt++) {
        bf16x8 bfr = *(const bf16x8*)&v_s[nt * 16 + l16][ks * 32 + quad * 8];
        o[nt] = __builtin_amdgcn_mfma_f32_16x16x32_bf16(a, bfr, o[nt], 0, 0, 0);
      }
    }
  }

  float inv_l[4];
  for (int r = 0; r < 4; r++) inv_l[r] = 1.f / fmaxf(l_prev[r], 1e-30f);
  for (int nt = 0; nt < 4; nt++) {
    int col = h * 64 + nt * 16 + l16;
    for (int r = 0; r < 4; r++) {
      int row = qt * 64 + wave * 16 + quad * 4 + r;
      xout[((size_t)(b * L_SEQ + row)) * 1024 + col] = (bf16)scrub(o[nt][r] * inv_l[r], 1e34f);
    }
  }
}

// ---------------------------------------------------------------------------
extern "C" void kernel_launch(void* const* d_in, const int* in_sizes, int n_in,
                              void* d_out, int out_size, void* d_ws, size_t ws_size,
                              hipStream_t stream) {
  const float* Q    = (const float*)d_in[0];
  const float* K    = (const float*)d_in[1];
  const float* V    = (const float*)d_in[2];
  const float* T    = (const float*)d_in[3];
  const int*   mask = (const int*)d_in[4];
  const float* WQ = (const float*)d_in[5];
  const float* bQ = (const float*)d_in[6];
  const float* WK = (const float*)d_in[7];
  const float* bK = (const float*)d_in[8];
  const float* WV = (const float*)d_in[9];
  const float* bV = (const float*)d_in[10];
  const float* WM = (const float*)d_in[11];
  const float* bM = (const float*)d_in[12];
  const float* WT = (const float*)d_in[13];
  const float* bT = (const float*)d_in[14];

  const size_t HEAD_ELEMS = (size_t)B_SZ * NH * L_SEQ * 64;  // 8388608
  bf16* ws = (bf16*)d_ws;
  bf16* qh = ws;                        // bf16, 16.8 MB
  bf16* kh = ws + HEAD_ELEMS;           // bf16, 16.8 MB
  bf16* vt = ws + 2 * HEAD_ELEMS;       // bf16, 16.8 MB
  bf16* tb = ws + 3 * HEAD_ELEMS;       // bf16, 1 MB   (total ws: 51.4 MB)
  // attn bf16 output lives in the upper half of d_out (f32 buffer, 33.6 MB)
  bf16* xa = (bf16*)d_out + HEAD_ELEMS;
  // final f32 GEMM result goes into ws[0..33.6MB] (qh+kh dead by then)
  float* fout = (float*)d_ws;

  dim3 blk(256);
  dim3 gg(8, 64);  // N/128, M/128 for 8192x1024 GEMMs

  gemm_bt<<<gg, blk, 0, stream>>>(Q, WQ, bQ, qh, 8192, 1024, 1024, /*aMode*/0, /*oMode*/1);
  gemm_bt<<<gg, blk, 0, stream>>>(K, WK, bK, kh, 8192, 1024, 1024, 0, 1);
  gemm_bt<<<gg, blk, 0, stream>>>(V, WV, bV, vt, 8192, 1024, 1024, 0, 2);
  t_proj<<<dim3(128), blk, 0, stream>>>(T, WT, bT, tb);
  attn<<<dim3(16, 128), blk, 0, stream>>>(qh, kh, vt, tb, mask, xa);
  gemm_bt<<<gg, blk, 0, stream>>>(xa, WM, bM, fout, 8192, 1024, 1024, /*aMode*/1, /*oMode*/0);
  hipMemcpyAsync(d_out, fout, HEAD_ELEMS * sizeof(float), hipMemcpyDeviceToDevice, stream);
}

// Round 4
// 497.925 us; speedup vs baseline: 1.3975x; 1.3975x over previous
//
#include <hip/hip_runtime.h>

typedef __bf16 bf16;
typedef __bf16 bf16x8 __attribute__((ext_vector_type(8)));
typedef float f32x4 __attribute__((ext_vector_type(4)));

#define B_SZ   8
#define L_SEQ  1024
#define NH     16

// async global->LDS, 16B per lane; lds base must be wave-uniform, data lands at
// base + lane*16 (m97 pattern: this is the 517->874 TF step).
__device__ __forceinline__ void lds_load16(bf16* lds, const bf16* g) {
  __builtin_amdgcn_global_load_lds(
      (const __attribute__((address_space(1))) void*)g,
      (__attribute__((address_space(3))) void*)lds, 16, 0, 0);
}

// load 8 contiguous f32 -> bf16x8
__device__ __forceinline__ bf16x8 cvt8(const float* __restrict__ p) {
  f32x4 a = *(const f32x4*)p;
  f32x4 b = *(const f32x4*)(p + 4);
  bf16x8 r;
  r[0] = (bf16)a[0]; r[1] = (bf16)a[1]; r[2] = (bf16)a[2]; r[3] = (bf16)a[3];
  r[4] = (bf16)b[0]; r[5] = (bf16)b[1]; r[6] = (bf16)b[2]; r[7] = (bf16)b[3];
  return r;
}

// ---------------------------------------------------------------------------
// f32 -> bf16 elementwise, 8 elems/thread
// ---------------------------------------------------------------------------
__global__ __launch_bounds__(256) void convert_k(const float* __restrict__ in,
                                                 bf16* __restrict__ out, int n8) {
  int i = blockIdx.x * 256 + threadIdx.x;
  if (i < n8) *(bf16x8*)&out[(size_t)i * 8] = cvt8(in + (size_t)i * 8);
}

// 4 weight matrices at once (blockIdx.y selects)
__global__ __launch_bounds__(256) void convert4_k(const float* p0, const float* p1,
                                                  const float* p2, const float* p3,
                                                  bf16* o0, bf16* o1, bf16* o2, bf16* o3,
                                                  int n8) {
  const float* in; bf16* out;
  switch (blockIdx.y) {
    case 0: in = p0; out = o0; break;
    case 1: in = p1; out = o1; break;
    case 2: in = p2; out = o2; break;
    default: in = p3; out = o3; break;
  }
  int i = blockIdx.x * 256 + threadIdx.x;
  if (i < n8) *(bf16x8*)&out[(size_t)i * 8] = cvt8(in + (size_t)i * 8);
}

// ---------------------------------------------------------------------------
// mask (B,1,L,L) int32 -> bit-packed u64 words: word[(b*L+row)*16 + kt] bit j
// = mask[b][row][kt*64+j] != 0.  33.5 MB -> 1 MB (L2-resident in attn).
// ---------------------------------------------------------------------------
__global__ __launch_bounds__(256) void pack_mask_k(const int* __restrict__ mask,
                                                   unsigned long long* __restrict__ out,
                                                   int nwords) {
  int w = blockIdx.x * 256 + threadIdx.x;
  if (w >= nwords) return;
  const int* base = mask + (size_t)w * 64;
  unsigned long long bits = 0;
  for (int j = 0; j < 64; j += 4) {
    int4 m4 = *(const int4*)(base + j);
    if (m4.x) bits |= 1ull << j;
    if (m4.y) bits |= 1ull << (j + 1);
    if (m4.z) bits |= 1ull << (j + 2);
    if (m4.w) bits |= 1ull << (j + 3);
  }
  out[w] = bits;
}

// ---------------------------------------------------------------------------
// GEMM: out = A @ W^T + bias.  A: MxK bf16 row-major, W: NxK bf16 row-major.
// m97 structure: global_load_lds width-16 staging into unpadded [128][64] LDS,
// 128x128 tile, BK=64, 4 waves 2x2, 4x4 16x16x32 MFMA per wave.
// oMode 0: f32 out row-major; oMode 1: bf16 out row-major.
// ---------------------------------------------------------------------------
__global__ __launch_bounds__(256) void gemm16(const bf16* __restrict__ A,
                                              const bf16* __restrict__ W,
                                              const float* __restrict__ bias,
                                              void* __restrict__ outp,
                                              int M, int N, int K, int oMode) {
  const int tid  = threadIdx.x;
  const int wave = tid >> 6;
  const int lane = tid & 63;
  const int quad = lane >> 4;
  const int l16  = lane & 15;
  const int wr   = wave >> 1;
  const int wc   = wave & 1;
  const int bm   = blockIdx.y * 128;
  const int bn   = blockIdx.x * 128;

  // unpadded: global_load_lds requires LDS contiguity in lane order
  __shared__ __align__(16) bf16 a_s[128 * 64];
  __shared__ __align__(16) bf16 b_s[128 * 64];

  const int lrow = lane >> 3;        // 0..7
  const int lcol = (lane & 7) * 8;   // 0,8,..,56

  f32x4 acc[4][4] = {};

  for (int kt = 0; kt < K; kt += 64) {
    __syncthreads();
    for (int i = 0; i < 4; i++) {
      int c = wave * 4 + i;            // chunk 0..15, rows c*8..c*8+7
      int row = c * 8 + lrow;
      lds_load16(&a_s[c * 512], &A[(size_t)(bm + row) * K + kt + lcol]);
      lds_load16(&b_s[c * 512], &W[(size_t)(bn + row) * K + kt + lcol]);
    }
    __syncthreads();

    for (int ks = 0; ks < 2; ks++) {
      bf16x8 af[4], bfr[4];
      for (int mt = 0; mt < 4; mt++)
        af[mt] = *(const bf16x8*)&a_s[(wr * 64 + mt * 16 + l16) * 64 + ks * 32 + quad * 8];
      for (int nt = 0; nt < 4; nt++)
        bfr[nt] = *(const bf16x8*)&b_s[(wc * 64 + nt * 16 + l16) * 64 + ks * 32 + quad * 8];
      for (int mt = 0; mt < 4; mt++)
        for (int nt = 0; nt < 4; nt++)
          acc[mt][nt] = __builtin_amdgcn_mfma_f32_16x16x32_bf16(af[mt], bfr[nt], acc[mt][nt], 0, 0, 0);
    }
  }

  for (int mt = 0; mt < 4; mt++) {
    for (int nt = 0; nt < 4; nt++) {
      int col = bn + wc * 64 + nt * 16 + l16;
      float bv = bias[col];
      for (int r = 0; r < 4; r++) {
        int i = bm + wr * 64 + mt * 16 + quad * 4 + r;
        float v = acc[mt][nt][r] + bv;
        if (oMode == 0) ((float*)outp)[(size_t)i * N + col] = v;
        else            ((bf16*)outp)[(size_t)i * N + col] = (bf16)v;
      }
    }
  }
}

// ---------------------------------------------------------------------------
// t = T @ WT^T + bT.  T: 8192x64 f32, WT: 64x64 f32.  out: 8192x64 bf16.
// ---------------------------------------------------------------------------
__global__ __launch_bounds__(256) void t_proj(const float* __restrict__ T,
                                              const float* __restrict__ WT,
                                              const float* __restrict__ bT,
                                              bf16* __restrict__ tout) {
  const int tid  = threadIdx.x;
  const int wave = tid >> 6;
  const int lane = tid & 63;
  const int quad = lane >> 4;
  const int l16  = lane & 15;
  const int row0 = blockIdx.x * 64;

  __shared__ __align__(16) bf16 t_s[64][72];
  __shared__ __align__(16) bf16 w_s[64][72];

  for (int i = 0; i < 2; i++) {
    int c = tid + i * 256;
    int r = c >> 3;
    int cg = (c & 7) * 8;
    *(bf16x8*)&t_s[r][cg] = cvt8(T + (size_t)(row0 + r) * 64 + cg);
    *(bf16x8*)&w_s[r][cg] = cvt8(WT + (size_t)r * 64 + cg);
  }
  __syncthreads();

  f32x4 acc[4] = {};
  for (int ks = 0; ks < 2; ks++) {
    bf16x8 a = *(const bf16x8*)&t_s[wave * 16 + l16][ks * 32 + quad * 8];
    for (int nt = 0; nt < 4; nt++) {
      bf16x8 b = *(const bf16x8*)&w_s[nt * 16 + l16][ks * 32 + quad * 8];
      acc[nt] = __builtin_amdgcn_mfma_f32_16x16x32_bf16(a, b, acc[nt], 0, 0, 0);
    }
  }
  for (int nt = 0; nt < 4; nt++) {
    int col = nt * 16 + l16;
    float bv = bT[col];
    for (int r = 0; r < 4; r++) {
      int row = row0 + wave * 16 + quad * 4 + r;
      tout[(size_t)row * 64 + col] = (bf16)(acc[nt][r] + bv);
    }
  }
}

// ---------------------------------------------------------------------------
// Flash attention per (bh, 64-row q-tile). q/k/v read from ROW-MAJOR (8192x1024)
// projections (head offset h*64); t from tb; mask from bit-packed u64.
// ---------------------------------------------------------------------------
__global__ __launch_bounds__(256) void attn(const bf16* __restrict__ qp,
                                            const bf16* __restrict__ kp,
                                            const bf16* __restrict__ vp,
                                            const bf16* __restrict__ tb,
                                            const unsigned long long* __restrict__ mb64,
                                            bf16* __restrict__ xout) {
  const int qt   = blockIdx.x;        // 0..15
  const int bh   = blockIdx.y;        // 0..127
  const int b    = bh >> 4;
  const int h    = bh & 15;
  const int tid  = threadIdx.x;
  const int wave = tid >> 6;
  const int lane = tid & 63;
  const int quad = lane >> 4;
  const int l16  = lane & 15;

  __shared__ __align__(16) bf16 q_s[64][136];
  __shared__ __align__(16) bf16 k_s[64][136];
  __shared__ __align__(16) bf16 v_s[64][72];   // [dv][l] (transposed in LDS)
  __shared__ __align__(16) bf16 p_s[64][72];

  const bf16* qpb = qp + (size_t)(b * L_SEQ) * 1024 + h * 64;   // row l -> +l*1024
  const bf16* kpb = kp + (size_t)(b * L_SEQ) * 1024 + h * 64;
  const bf16* vpb = vp + (size_t)(b * L_SEQ) * 1024 + h * 64;
  const bf16* tb0 = tb + (size_t)b * L_SEQ * 64;
  const unsigned long long* mrow = mb64 + (size_t)b * L_SEQ * 16;

  // q tile 64x128: cols 0..63 from qpb, 64..127 from tb
  for (int i = 0; i < 4; i++) {
    int c = tid + i * 256;
    int row = c >> 4;
    int cg = c & 15;
    int gl = qt * 64 + row;
    const bf16* src = (cg < 8) ? (qpb + (size_t)gl * 1024 + cg * 8)
                               : (tb0 + (size_t)gl * 64 + (cg - 8) * 8);
    *(bf16x8*)&q_s[row][cg * 8] = *(const bf16x8*)src;
  }

  f32x4 o[4] = {};
  float m_prev[4], l_prev[4];
  for (int r = 0; r < 4; r++) { m_prev[r] = -1e30f; l_prev[r] = 0.f; }

  const float scale = 0.08838834764831845f;  // 1/sqrt(128)
  const int qrow_base = qt * 64 + wave * 16 + quad * 4;

  for (int kt = 0; kt < 16; kt++) {
    __syncthreads();
    // k tile 64x128
    for (int i = 0; i < 4; i++) {
      int c = tid + i * 256;
      int row = c >> 4;
      int cg = c & 15;
      int gl = kt * 64 + row;
      const bf16* src = (cg < 8) ? (kpb + (size_t)gl * 1024 + cg * 8)
                                 : (tb0 + (size_t)gl * 64 + (cg - 8) * 8);
      *(bf16x8*)&k_s[row][cg * 8] = *(const bf16x8*)src;
    }
    // v tile: transpose to [dv][l]; lanes span l -> conflict-free LDS writes
    for (int i = 0; i < 2; i++) {
      int c = tid + i * 256;
      int dvb = (c >> 6) * 8;
      int l = c & 63;
      bf16x8 vv = *(const bf16x8*)&vpb[(size_t)(kt * 64 + l) * 1024 + dvb];
      for (int j = 0; j < 8; j++) v_s[dvb + j][l] = vv[j];
    }
    __syncthreads();

    // S = q_cat @ k_cat^T (K=128)
    f32x4 s_acc[4] = {};
    for (int ks = 0; ks < 4; ks++) {
      bf16x8 a = *(const bf16x8*)&q_s[wave * 16 + l16][ks * 32 + quad * 8];
      for (int nt = 0; nt < 4; nt++) {
        bf16x8 bfr = *(const bf16x8*)&k_s[nt * 16 + l16][ks * 32 + quad * 8];
        s_acc[nt] = __builtin_amdgcn_mfma_f32_16x16x32_bf16(a, bfr, s_acc[nt], 0, 0, 0);
      }
    }

    // scale + bitmask (4 u64 loads instead of 16 int32 loads)
    float sv[4][4];
    for (int r = 0; r < 4; r++) {
      unsigned long long w = mrow[(size_t)(qrow_base + r) * 16 + kt];
      for (int nt = 0; nt < 4; nt++) {
        int bit = (int)((w >> (nt * 16 + l16)) & 1ull);
        sv[nt][r] = bit ? -1e9f : s_acc[nt][r] * scale;
      }
    }

    // online softmax per row (rows replicated across quad's 16 lanes)
    float alpha[4];
    for (int r = 0; r < 4; r++) {
      float mx = fmaxf(fmaxf(sv[0][r], sv[1][r]), fmaxf(sv[2][r], sv[3][r]));
      for (int off = 8; off >= 1; off >>= 1) mx = fmaxf(mx, __shfl_xor(mx, off));
      float m_new = fmaxf(m_prev[r], mx);
      alpha[r] = __expf(m_prev[r] - m_new);
      float rowsum = 0.f;
      for (int nt = 0; nt < 4; nt++) {
        float p = __expf(sv[nt][r] - m_new);
        sv[nt][r] = p;
        rowsum += p;
      }
      for (int off = 8; off >= 1; off >>= 1) rowsum += __shfl_xor(rowsum, off);
      l_prev[r] = l_prev[r] * alpha[r] + rowsum;
      m_prev[r] = m_new;
    }
    for (int nt = 0; nt < 4; nt++)
      for (int r = 0; r < 4; r++) o[nt][r] *= alpha[r];

    // P: C-layout -> LDS bf16
    for (int nt = 0; nt < 4; nt++)
      for (int r = 0; r < 4; r++)
        p_s[wave * 16 + quad * 4 + r][nt * 16 + l16] = (bf16)sv[nt][r];
    __syncthreads();

    // O += P @ V (K=64); B-operand = v_s [dv][l]
    for (int ks = 0; ks < 2; ks++) {
      bf16x8 a = *(const bf16x8*)&p_s[wave * 16 + l16][ks * 32 + quad * 8];
      for (int nt = 0; nt < 4; nt++) {
        bf16x8 bfr = *(const bf16x8*)&v_s[nt * 16 + l16][ks * 32 + quad * 8];
        o[nt] = __builtin_amdgcn_mfma_f32_16x16x32_bf16(a, bfr, o[nt], 0, 0, 0);
      }
    }
  }

  float inv_l[4];
  for (int r = 0; r < 4; r++) inv_l[r] = 1.f / fmaxf(l_prev[r], 1e-30f);
  for (int nt = 0; nt < 4; nt++) {
    int col = h * 64 + nt * 16 + l16;
    for (int r = 0; r < 4; r++) {
      int row = qt * 64 + wave * 16 + quad * 4 + r;
      xout[((size_t)(b * L_SEQ + row)) * 1024 + col] = (bf16)(o[nt][r] * inv_l[r]);
    }
  }
}

// ---------------------------------------------------------------------------
extern "C" void kernel_launch(void* const* d_in, const int* in_sizes, int n_in,
                              void* d_out, int out_size, void* d_ws, size_t ws_size,
                              hipStream_t stream) {
  const float* Q    = (const float*)d_in[0];
  const float* K    = (const float*)d_in[1];
  const float* V    = (const float*)d_in[2];
  const float* T    = (const float*)d_in[3];
  const int*   mask = (const int*)d_in[4];
  const float* WQ = (const float*)d_in[5];
  const float* bQ = (const float*)d_in[6];
  const float* WK = (const float*)d_in[7];
  const float* bK = (const float*)d_in[8];
  const float* WV = (const float*)d_in[9];
  const float* bV = (const float*)d_in[10];
  const float* WM = (const float*)d_in[11];
  const float* bM = (const float*)d_in[12];
  const float* WT = (const float*)d_in[13];
  const float* bT = (const float*)d_in[14];

  const size_t NE = (size_t)B_SZ * NH * L_SEQ * 64;  // 8388608 (= 8192x1024)
  bf16* ws16 = (bf16*)d_ws;
  bf16* qp = ws16;                    // bf16 8192x1024
  bf16* kp = ws16 + NE;
  bf16* vp = ws16 + 2 * NE;
  bf16* tb = ws16 + 3 * NE;                         // 524288 elems
  unsigned long long* mb64 = (unsigned long long*)(ws16 + 3 * NE + 524288);  // 131072 u64
  bf16* wq = ws16 + 3 * NE + 1048576;               // 4 x 1048576 elems
  bf16* wk = wq + 1048576;
  bf16* wv = wk + 1048576;
  bf16* wm = wv + 1048576;
  // ws peak: 30,408,704 bf16 = 58 MB
  bf16* abuf = (bf16*)d_out;          // d_out lower half = A-conversion scratch
  bf16* xa   = (bf16*)d_out + NE;     // d_out upper half = attn output
  float* fout = (float*)d_ws;         // final f32 out over qp+kp (dead then)

  dim3 blk(256);
  dim3 gg(8, 64);   // N/128, M/128

  pack_mask_k<<<dim3(512), blk, 0, stream>>>(mask, mb64, 131072);
  convert4_k<<<dim3(512, 4), blk, 0, stream>>>(WQ, WK, WV, WM, wq, wk, wv, wm, 131072);
  t_proj<<<dim3(128), blk, 0, stream>>>(T, WT, bT, tb);

  convert_k<<<dim3(4096), blk, 0, stream>>>(Q, abuf, 1048576);
  gemm16<<<gg, blk, 0, stream>>>(abuf, wq, bQ, qp, 8192, 1024, 1024, 1);
  convert_k<<<dim3(4096), blk, 0, stream>>>(K, abuf, 1048576);
  gemm16<<<gg, blk, 0, stream>>>(abuf, wk, bK, kp, 8192, 1024, 1024, 1);
  convert_k<<<dim3(4096), blk, 0, stream>>>(V, abuf, 1048576);
  gemm16<<<gg, blk, 0, stream>>>(abuf, wv, bV, vp, 8192, 1024, 1024, 1);

  attn<<<dim3(16, 128), blk, 0, stream>>>(qp, kp, vp, tb, mb64, xa);

  gemm16<<<gg, blk, 0, stream>>>(xa, wm, bM, fout, 8192, 1024, 1024, 0);
  hipMemcpyAsync(d_out, fout, NE * sizeof(float), hipMemcpyDeviceToDevice, stream);
}